// Round 1
// baseline (403.148 us; speedup 1.0000x reference)
//
#include <hip/hip_runtime.h>

#define B  32
#define T  8192
#define H  256
#define NC 32      // T-chunks per batch
#define CT 256     // rows per chunk (NC*CT == T)
#define VQ 8       // o-slices for k_v partials
#define TILE 8     // rows per softmax tile (independent shuffle chains)

// ---------------------------------------------------------------------------
// Kernel 1: vpart[q][b][h] = sum_{o in slice q} W1[o,h] * h_t[b,o]
// (v[b] = W1^T h_t[b]; score[b,t] = hs[b,t,:].v[b] replaces the big einsum)
// ---------------------------------------------------------------------------
__global__ void k_v(const float* __restrict__ hs,
                    const float* __restrict__ W1,
                    float* __restrict__ vpart) {
    int b = blockIdx.x, q = blockIdx.y, tid = threadIdx.x;  // 256 threads
    __shared__ float ht[32];
    if (tid < 32) ht[tid] = hs[((size_t)(b * T + (T - 1))) * H + q * 32 + tid];
    __syncthreads();
    float acc = 0.f;
    #pragma unroll
    for (int o = 0; o < 32; ++o)
        acc += W1[(q * 32 + o) * H + tid] * ht[o];   // coalesced over tid
    vpart[((size_t)(q * B + b)) * H + tid] = acc;
}

// ---------------------------------------------------------------------------
// Kernel 2 (fused, single pass over hs). Restructured from row-at-a-time to
// 8-row tiles:
//   - 8 independent float4 loads batched (deep MLP, sustains HBM BW)
//   - 8 interleaved 6-step xor-shuffle reduces (throughput, not latency)
//   - per-TILE online-softmax rescale (serial m->exp->l,c chain 8x shorter)
//   - coalesced 8-lane score store instead of lane-0 scatter
// ---------------------------------------------------------------------------
__global__ void __launch_bounds__(256, 4)
k_fused(const float* __restrict__ hs,
        const float* __restrict__ vpart,
        float* __restrict__ score,
        float* __restrict__ mpart,
        float* __restrict__ lpart,
        float* __restrict__ ctxp) {
    int b = blockIdx.x, tc = blockIdx.y;
    int tid = threadIdx.x, wave = tid >> 6, lane = tid & 63;
    __shared__ float vs[H];
    __shared__ float wm[4], wl[4];
    __shared__ float wctx[4][H];

    float vv = 0.f;
    #pragma unroll
    for (int q = 0; q < VQ; ++q)
        vv += vpart[((size_t)(q * B + b)) * H + tid];
    vs[tid] = vv;
    __syncthreads();
    float v0 = vs[lane * 4 + 0], v1 = vs[lane * 4 + 1];
    float v2 = vs[lane * 4 + 2], v3 = vs[lane * 4 + 3];

    const float* base = hs + ((size_t)(b * T + tc * CT)) * H + lane * 4;
    float m = -1e30f, l = 0.f;
    float c0 = 0.f, c1 = 0.f, c2 = 0.f, c3 = 0.f;

    for (int tile = 0; tile < 64 / TILE; ++tile) {
        int row0 = wave * 64 + tile * TILE;

        // batched independent loads (coalesced 1 KB per wave per row)
        float4 u[TILE];
        #pragma unroll
        for (int r = 0; r < TILE; ++r)
            u[r] = *(const float4*)(base + (size_t)(row0 + r) * H);

        // per-lane partial dots (4 cols each)
        float s[TILE];
        #pragma unroll
        for (int r = 0; r < TILE; ++r)
            s[r] = u[r].x * v0 + u[r].y * v1 + u[r].z * v2 + u[r].w * v3;

        // TILE independent 6-step butterfly reduces, interleaved
        #pragma unroll
        for (int mk = 1; mk < 64; mk <<= 1) {
            #pragma unroll
            for (int r = 0; r < TILE; ++r)
                s[r] += __shfl_xor(s[r], mk, 64);
        }

        // coalesced score store: lane r writes row row0+r
        float sel = s[0];
        #pragma unroll
        for (int r = 1; r < TILE; ++r)
            sel = (lane == r) ? s[r] : sel;
        if (lane < TILE)
            score[b * T + tc * CT + row0 + lane] = sel;

        // one online-softmax rescale per tile (not per row)
        float mt = s[0];
        #pragma unroll
        for (int r = 1; r < TILE; ++r) mt = fmaxf(mt, s[r]);
        float mn = fmaxf(m, mt);
        float al = __expf(m - mn);           // first tile: __expf(-huge) = 0
        float ps = 0.f, a0 = 0.f, a1 = 0.f, a2 = 0.f, a3 = 0.f;
        #pragma unroll
        for (int r = 0; r < TILE; ++r) {
            float p = __expf(s[r] - mn);
            ps += p;
            a0 += p * u[r].x; a1 += p * u[r].y;
            a2 += p * u[r].z; a3 += p * u[r].w;
        }
        l  = l  * al + ps;
        c0 = c0 * al + a0; c1 = c1 * al + a1;
        c2 = c2 * al + a2; c3 = c3 * al + a3;
        m  = mn;
    }

    if (lane == 0) { wm[wave] = m; wl[wave] = l; }
    wctx[wave][lane * 4 + 0] = c0;
    wctx[wave][lane * 4 + 1] = c1;
    wctx[wave][lane * 4 + 2] = c2;
    wctx[wave][lane * 4 + 3] = c3;
    __syncthreads();

    float bm = fmaxf(fmaxf(wm[0], wm[1]), fmaxf(wm[2], wm[3]));
    float e0 = __expf(wm[0] - bm), e1 = __expf(wm[1] - bm);
    float e2 = __expf(wm[2] - bm), e3 = __expf(wm[3] - bm);
    float cc = wctx[0][tid] * e0 + wctx[1][tid] * e1
             + wctx[2][tid] * e2 + wctx[3][tid] * e3;
    ctxp[((size_t)(b * NC + tc)) * H + tid] = cc;
    if (tid == 0) {
        mpart[b * NC + tc] = bm;
        lpart[b * NC + tc] = wl[0] * e0 + wl[1] * e1 + wl[2] * e2 + wl[3] * e3;
    }
}

// ---------------------------------------------------------------------------
// Kernel 3 (epilogue, one launch): grid (B, NC+1).
//   y <  NC : attention_weights for 256 t's.
//   y == NC : combine chunk ctx partials; out_av = tanh([ctx,h_t] @ W2^T).
// ---------------------------------------------------------------------------
__global__ void k_epi(const float* __restrict__ hs,
                      const float* __restrict__ W2,
                      const float* __restrict__ score,
                      const float* __restrict__ mpart,
                      const float* __restrict__ lpart,
                      const float* __restrict__ ctxp,
                      float* __restrict__ out_av,
                      float* __restrict__ out_aw) {
    int b = blockIdx.x, y = blockIdx.y, tid = threadIdx.x;  // 256 threads

    float M = -1e30f;
    #pragma unroll
    for (int c = 0; c < NC; ++c) M = fmaxf(M, mpart[b * NC + c]);
    float L = 0.f;
    #pragma unroll
    for (int c = 0; c < NC; ++c) L += lpart[b * NC + c] * __expf(mpart[b * NC + c] - M);

    if (y < NC) {
        int t = y * CT + tid;
        out_aw[b * T + t] = __expf(score[b * T + t] - M) * (1.0f / L);
        return;
    }

    // y == NC: attention_vector for batch b
    __shared__ float pre[2 * H];
    float cc = 0.f;
    #pragma unroll
    for (int c = 0; c < NC; ++c)
        cc += ctxp[((size_t)(b * NC + c)) * H + tid] * __expf(mpart[b * NC + c] - M);
    pre[tid]     = cc / L;
    pre[H + tid] = hs[((size_t)(b * T + (T - 1))) * H + tid];
    __syncthreads();
    const float4* w2r = (const float4*)(W2 + (size_t)tid * (2 * H));
    float acc = 0.f;
    #pragma unroll 4
    for (int j = 0; j < (2 * H) / 4; ++j) {
        float4 u = w2r[j];
        acc += pre[4 * j + 0] * u.x + pre[4 * j + 1] * u.y
             + pre[4 * j + 2] * u.z + pre[4 * j + 3] * u.w;
    }
    out_av[b * H + tid] = tanhf(acc);
}

extern "C" void kernel_launch(void* const* d_in, const int* in_sizes, int n_in,
                              void* d_out, int out_size, void* d_ws, size_t ws_size,
                              hipStream_t stream) {
    const float* hs = (const float*)d_in[0];
    const float* W1 = (const float*)d_in[1];
    const float* W2 = (const float*)d_in[2];
    float* out    = (float*)d_out;
    float* out_av = out;              // attention_vector  [B*H  = 8192]
    float* out_aw = out + B * H;      // attention_weights [B*T  = 262144]

    float* ws    = (float*)d_ws;
    float* vpart = ws;                              // VQ*B*H   = 65536
    float* score = vpart + VQ * B * H;              // B*T      = 262144
    float* mpart = score + B * T;                   // B*NC     = 1024
    float* lpart = mpart + B * NC;                  // 1024
    float* ctxp  = lpart + B * NC;                  // B*NC*H   = 262144
    // total ws: ~2.4 MB

    k_v     <<<dim3(B, VQ),     256, 0, stream>>>(hs, W1, vpart);
    k_fused <<<dim3(B, NC),     256, 0, stream>>>(hs, vpart, score, mpart, lpart, ctxp);
    k_epi   <<<dim3(B, NC + 1), 256, 0, stream>>>(hs, W2, score, mpart, lpart, ctxp,
                                                  out_av, out_aw);
}

// Round 2
// 379.344 us; speedup vs baseline: 1.0627x; 1.0627x over previous
//
#include <hip/hip_runtime.h>

#define B  32
#define T  8192
#define H  256
#define NC 32      // T-chunks per batch
#define CT 256     // rows per chunk (NC*CT == T)
#define VQ 8       // o-slices for k_v partials

// ---------------------------------------------------------------------------
// Kernel 1: vpart[q][b][h] = sum_{o in slice q} W1[o,h] * h_t[b,o]
// (v[b] = W1^T h_t[b]; score[b,t] = hs[b,t,:].v[b] replaces the big einsum)
// ---------------------------------------------------------------------------
__global__ void k_v(const float* __restrict__ hs,
                    const float* __restrict__ W1,
                    float* __restrict__ vpart) {
    int b = blockIdx.x, q = blockIdx.y, tid = threadIdx.x;  // 256 threads
    __shared__ float ht[32];
    if (tid < 32) ht[tid] = hs[((size_t)(b * T + (T - 1))) * H + q * 32 + tid];
    __syncthreads();
    float acc = 0.f;
    #pragma unroll
    for (int o = 0; o < 32; ++o)
        acc += W1[(q * 32 + o) * H + tid] * ht[o];   // coalesced over tid
    vpart[((size_t)(q * B + b)) * H + tid] = acc;
}

// ---------------------------------------------------------------------------
// Kernel 2 (fused, single pass over hs): per (b, chunk) block of 256 rows:
//   raw score[b,t] (to ws) + online-softmax partials (m,l) + partial context.
// R0-proven core (row-at-a-time, small register footprint) + a 2-deep
// register prefetch: row i+1's float4 is in flight while row i is reduced.
// Clamped index (min(i+1,63)) keeps the last iteration in bounds, branch-free.
// ---------------------------------------------------------------------------
__global__ void __launch_bounds__(256, 4)
k_fused(const float* __restrict__ hs,
        const float* __restrict__ vpart,
        float* __restrict__ score,
        float* __restrict__ mpart,
        float* __restrict__ lpart,
        float* __restrict__ ctxp) {
    int b = blockIdx.x, tc = blockIdx.y;
    int tid = threadIdx.x, wave = tid >> 6, lane = tid & 63;
    __shared__ float vs[H];
    __shared__ float wm[4], wl[4];
    __shared__ float wctx[4][H];

    float vv = 0.f;
    #pragma unroll
    for (int q = 0; q < VQ; ++q)
        vv += vpart[((size_t)(q * B + b)) * H + tid];
    vs[tid] = vv;
    __syncthreads();
    float v0 = vs[lane * 4 + 0], v1 = vs[lane * 4 + 1];
    float v2 = vs[lane * 4 + 2], v3 = vs[lane * 4 + 3];

    // per-wave base: wave owns rows [wave*64, wave*64+64)
    const float* basew = hs + ((size_t)(b * T + tc * CT + wave * 64)) * H + lane * 4;
    float m = -1e30f, l = 0.f;
    float c0 = 0.f, c1 = 0.f, c2 = 0.f, c3 = 0.f;

    float4 u = *(const float4*)(basew);          // prefetch row 0
    for (int i = 0; i < 64; ++i) {
        int inext = (i + 1 < 64) ? i + 1 : 63;   // clamp: redundant re-load on last iter
        float4 un = *(const float4*)(basew + (size_t)inext * H);

        float s = u.x * v0 + u.y * v1 + u.z * v2 + u.w * v3;
        #pragma unroll
        for (int mk = 1; mk < 64; mk <<= 1)
            s += __shfl_xor(s, mk, 64);          // all lanes end with full dot
        if (lane == 0)
            score[b * T + tc * CT + wave * 64 + i] = s;
        float mn = fmaxf(m, s);
        float al = __expf(m - mn);               // first iter: __expf(-huge) = 0
        float p  = __expf(s - mn);
        l  = l  * al + p;
        c0 = c0 * al + p * u.x;
        c1 = c1 * al + p * u.y;
        c2 = c2 * al + p * u.z;
        c3 = c3 * al + p * u.w;
        m  = mn;
        u  = un;
    }

    if (lane == 0) { wm[wave] = m; wl[wave] = l; }
    wctx[wave][lane * 4 + 0] = c0;
    wctx[wave][lane * 4 + 1] = c1;
    wctx[wave][lane * 4 + 2] = c2;
    wctx[wave][lane * 4 + 3] = c3;
    __syncthreads();

    float bm = fmaxf(fmaxf(wm[0], wm[1]), fmaxf(wm[2], wm[3]));
    float e0 = __expf(wm[0] - bm), e1 = __expf(wm[1] - bm);
    float e2 = __expf(wm[2] - bm), e3 = __expf(wm[3] - bm);
    float cc = wctx[0][tid] * e0 + wctx[1][tid] * e1
             + wctx[2][tid] * e2 + wctx[3][tid] * e3;
    ctxp[((size_t)(b * NC + tc)) * H + tid] = cc;
    if (tid == 0) {
        mpart[b * NC + tc] = bm;
        lpart[b * NC + tc] = wl[0] * e0 + wl[1] * e1 + wl[2] * e2 + wl[3] * e3;
    }
}

// ---------------------------------------------------------------------------
// Kernel 3 (epilogue, one launch): grid (B, NC+1).
//   y <  NC : attention_weights for 256 t's.
//   y == NC : combine chunk ctx partials; out_av = tanh([ctx,h_t] @ W2^T).
// ---------------------------------------------------------------------------
__global__ void k_epi(const float* __restrict__ hs,
                      const float* __restrict__ W2,
                      const float* __restrict__ score,
                      const float* __restrict__ mpart,
                      const float* __restrict__ lpart,
                      const float* __restrict__ ctxp,
                      float* __restrict__ out_av,
                      float* __restrict__ out_aw) {
    int b = blockIdx.x, y = blockIdx.y, tid = threadIdx.x;  // 256 threads

    float M = -1e30f;
    #pragma unroll
    for (int c = 0; c < NC; ++c) M = fmaxf(M, mpart[b * NC + c]);
    float L = 0.f;
    #pragma unroll
    for (int c = 0; c < NC; ++c) L += lpart[b * NC + c] * __expf(mpart[b * NC + c] - M);

    if (y < NC) {
        int t = y * CT + tid;
        out_aw[b * T + t] = __expf(score[b * T + t] - M) * (1.0f / L);
        return;
    }

    // y == NC: attention_vector for batch b
    __shared__ float pre[2 * H];
    float cc = 0.f;
    #pragma unroll
    for (int c = 0; c < NC; ++c)
        cc += ctxp[((size_t)(b * NC + c)) * H + tid] * __expf(mpart[b * NC + c] - M);
    pre[tid]     = cc / L;
    pre[H + tid] = hs[((size_t)(b * T + (T - 1))) * H + tid];
    __syncthreads();
    const float4* w2r = (const float4*)(W2 + (size_t)tid * (2 * H));
    float acc = 0.f;
    #pragma unroll 4
    for (int j = 0; j < (2 * H) / 4; ++j) {
        float4 u = w2r[j];
        acc += pre[4 * j + 0] * u.x + pre[4 * j + 1] * u.y
             + pre[4 * j + 2] * u.z + pre[4 * j + 3] * u.w;
    }
    out_av[b * H + tid] = tanhf(acc);
}

extern "C" void kernel_launch(void* const* d_in, const int* in_sizes, int n_in,
                              void* d_out, int out_size, void* d_ws, size_t ws_size,
                              hipStream_t stream) {
    const float* hs = (const float*)d_in[0];
    const float* W1 = (const float*)d_in[1];
    const float* W2 = (const float*)d_in[2];
    float* out    = (float*)d_out;
    float* out_av = out;              // attention_vector  [B*H  = 8192]
    float* out_aw = out + B * H;      // attention_weights [B*T  = 262144]

    float* ws    = (float*)d_ws;
    float* vpart = ws;                              // VQ*B*H   = 65536
    float* score = vpart + VQ * B * H;              // B*T      = 262144
    float* mpart = score + B * T;                   // B*NC     = 1024
    float* lpart = mpart + B * NC;                  // 1024
    float* ctxp  = lpart + B * NC;                  // B*NC*H   = 262144
    // total ws: ~2.4 MB

    k_v     <<<dim3(B, VQ),     256, 0, stream>>>(hs, W1, vpart);
    k_fused <<<dim3(B, NC),     256, 0, stream>>>(hs, vpart, score, mpart, lpart, ctxp);
    k_epi   <<<dim3(B, NC + 1), 256, 0, stream>>>(hs, W2, score, mpart, lpart, ctxp,
                                                  out_av, out_aw);
}